// Round 4
// baseline (277.221 us; speedup 1.0000x reference)
//
#include <hip/hip_runtime.h>
#include <hip/hip_bf16.h>
#include <math.h>

#define C_IN 256
#define H_   64
#define W_   64
#define B_   8
#define COUT 256
#define HW   (H_*W_)

typedef float f32x4 __attribute__((ext_vector_type(4)));
typedef float f32x2 __attribute__((ext_vector_type(2)));
typedef short short8 __attribute__((ext_vector_type(8)));
typedef int   i32x4 __attribute__((ext_vector_type(4)));

union cvt8 { i32x4 v; short8 s; };

static __device__ __forceinline__ int pack_bf16x2(float a, float b) {
    union { float f; unsigned u; } x, y;
    x.f = a; y.f = b;
    unsigned lo = (x.u + 0x7fffu + ((x.u >> 16) & 1u)) >> 16;
    unsigned hi = (y.u + 0x7fffu + ((y.u >> 16) & 1u)) & 0xffff0000u;
    return (int)(lo | hi);
}

static __device__ __forceinline__ f32x2 up2(int v) {
    union { int i; float f; } a, b;
    a.i = v << 16; b.i = v & 0xffff0000;
    return (f32x2){a.f, b.f};
}

static __device__ __forceinline__ int pk2(f32x2 r) {
    return pack_bf16x2(r[0], r[1]);
}

// ---------------------------------------------------------------------------
// Prep: weights -> bf16, K-order tap-major.
//   wR[k][o][c] (9 x 256 x 256), wO[k][o][c] (9 x 32 x 256, o>=18 zero)
// ---------------------------------------------------------------------------
__global__ __launch_bounds__(256) void prep_weights_kernel(
    const float* __restrict__ ow, const float* __restrict__ dw,
    short* __restrict__ wR, short* __restrict__ wO)
{
    int blk = blockIdx.x;
    int k   = blk / 288;
    int row = blk % 288;
    int c   = threadIdx.x;
    union { float f; unsigned u; } a;
    if (row < 256) {
        a.f = dw[(size_t)row * 2304 + c * 9 + k];
        unsigned r = (a.u + 0x7fffu + ((a.u >> 16) & 1u)) >> 16;
        wR[(size_t)k * 65536 + row * 256 + c] = (short)r;
    } else {
        int o = row - 256;
        a.f = (o < 18) ? ow[(size_t)o * 2304 + c * 9 + k] : 0.f;
        unsigned r = (a.u + 0x7fffu + ((a.u >> 16) & 1u)) >> 16;
        wO[(size_t)k * 8192 + o * 256 + c] = (short)r;
    }
}

// ---------------------------------------------------------------------------
// Transpose x: NCHW fp32 -> NHWC bf16  xT[b][h][w][c]. One block per (b,h).
// HBM-bound (~200 MB); LDS conflicts negligible at this volume.
// ---------------------------------------------------------------------------
__global__ __launch_bounds__(256) void transpose_x_kernel(
    const float* __restrict__ x, unsigned short* __restrict__ xT)
{
    __shared__ float tile[64][257];
    const int tid = threadIdx.x;
    const float* xb = x + ((size_t)(blockIdx.x >> 6) << 20) + (blockIdx.x & 63) * 64;

#pragma unroll
    for (int pass = 0; pass < 16; ++pass) {
        int c  = pass * 16 + (tid >> 4);
        int w0 = (tid & 15) * 4;
        float4 v = *(const float4*)(xb + (size_t)c * 4096 + w0);
        tile[w0][c] = v.x; tile[w0 + 1][c] = v.y;
        tile[w0 + 2][c] = v.z; tile[w0 + 3][c] = v.w;
    }
    __syncthreads();

    int4* ob = (int4*)(xT + ((size_t)blockIdx.x << 14));
#pragma unroll
    for (int pass = 0; pass < 8; ++pass) {
        int idx = pass * 256 + tid;
        int w = idx >> 5, ch8 = idx & 31;
        const float* tr = &tile[w][ch8 * 8];
        int4 pk;
        pk.x = pack_bf16x2(tr[0], tr[1]);
        pk.y = pack_bf16x2(tr[2], tr[3]);
        pk.z = pack_bf16x2(tr[4], tr[5]);
        pk.w = pack_bf16x2(tr[6], tr[7]);
        ob[idx] = pk;
    }
}

// ---------------------------------------------------------------------------
// Offset conv via bf16 MFMA, NHWC input. ZERO LDS, ZERO barriers:
// waves own disjoint px-tiles, so B fragments load directly in MFMA layout
// (masked shifted copy); A fragments direct from L2-resident wO (nt).
// One block per (b,ho), b = blk&7 (XCD pin). 64 px x 32 o.
// ---------------------------------------------------------------------------
__global__ __launch_bounds__(256, 4) void offset_mfma_kernel(
    const unsigned short* __restrict__ xT, const short* __restrict__ wO,
    float* __restrict__ offs)
{
    const int tid = threadIdx.x;
    const int b   = blockIdx.x & 7;
    const int ho  = blockIdx.x >> 3;

    const int wv = tid >> 6;
    const int ln = tid & 63;
    const int lo = ln & 15;
    const int quad = ln >> 4;
    const int pxl = wv * 16 + lo;          // this lane's px (B operand n)

    f32x4 acc[2];
    acc[0] = (f32x4){0.f, 0.f, 0.f, 0.f};
    acc[1] = (f32x4){0.f, 0.f, 0.f, 0.f};

    const unsigned short* xbb = xT + ((size_t)b << 20);
    const i32x4 z4 = {0, 0, 0, 0};

    for (int s = 0; s < 36; ++s) {
        int c4 = s / 9, k = s - c4 * 9, c0 = c4 << 6;
        int yy = ho + k / 3 - 1;
        int xx = pxl + k % 3 - 1;
        bool valid = (yy >= 0) & (yy < 64) & (xx >= 0) & (xx < 64);
        int yc = min(max(yy, 0), 63), xc = min(max(xx, 0), 63);
        const unsigned short* src = xbb + (((size_t)yc * 64 + xc) << 8) + c0 + quad * 8;

        i32x4 bf[2];
#pragma unroll
        for (int ks = 0; ks < 2; ++ks)
            bf[ks] = valid ? *(const i32x4*)(src + ks * 32) : z4;

        const short* wb = wO + k * 8192 + lo * 256 + c0 + quad * 8;
        i32x4 af[2][2];
#pragma unroll
        for (int t = 0; t < 2; ++t)
#pragma unroll
            for (int ks = 0; ks < 2; ++ks)
                af[t][ks] = __builtin_nontemporal_load(
                    (const i32x4*)(wb + t * 4096 + ks * 32));

#pragma unroll
        for (int ks = 0; ks < 2; ++ks) {
            cvt8 bb; bb.v = bf[ks];
#pragma unroll
            for (int t = 0; t < 2; ++t) {
                cvt8 aa; aa.v = af[t][ks];
                acc[t] = __builtin_amdgcn_mfma_f32_16x16x32_bf16(aa.s, bb.s, acc[t], 0, 0, 0);
            }
        }
    }

#pragma unroll
    for (int t = 0; t < 2; ++t) {
#pragma unroll
        for (int r = 0; r < 4; ++r) {
            int o = t * 16 + quad * 4 + r;
            if (o < 18)
                offs[((size_t)b * 18 + o) * HW + ho * 64 + pxl] = acc[t][r];
        }
    }
}

// ---------------------------------------------------------------------------
// Deformable conv via bf16 MFMA. One block per (b,ho), b = blk&7 (XCD pin).
// 64 px x 256 o. A fragments: direct global->VGPR (nt, L2-resident).
// B (patches): bilinear blend -> double-buffered LDS, ONE barrier per stage.
// Stage order c-chunk-major (9 taps consecutive) for corner L1/L2 locality.
// ---------------------------------------------------------------------------
__global__ __launch_bounds__(256, 3) void deform_mfma_kernel(
    const unsigned short* __restrict__ xT, const float* __restrict__ offs,
    const short* __restrict__ wR, float* __restrict__ y,
    float* __restrict__ sum_, float* __restrict__ sumsq_)
{
    __shared__ int4   meta_i[576];
    __shared__ float4 meta_w[576];
    __shared__ int4   bT[2][64 * 8];

    const int tid = threadIdx.x;
    const int b   = blockIdx.x & 7;
    const int ho  = blockIdx.x >> 3;

    for (int e = tid; e < 576; e += 256) {
        int kk = e >> 6;
        int pxe = e & 63;
        float dy = offs[((size_t)b * 18 + 2 * kk)     * HW + ho * W_ + pxe];
        float dx = offs[((size_t)b * 18 + 2 * kk + 1) * HW + ho * W_ + pxe];
        float sy = (float)(ho - 1 + kk / 3) + dy;
        float sx = (float)(pxe - 1 + kk % 3) + dx;
        float y0f = floorf(sy), x0f = floorf(sx);
        float ly = sy - y0f, lx = sx - x0f;
        int y0 = (int)y0f, x0 = (int)x0f;
        int y1 = y0 + 1, x1 = x0 + 1;
        float wy0 = 1.f - ly, wy1 = ly, wx0 = 1.f - lx, wx1 = lx;
        bool vy0 = (y0 >= 0) & (y0 < H_), vy1 = (y1 >= 0) & (y1 < H_);
        bool vx0 = (x0 >= 0) & (x0 < W_), vx1 = (x1 >= 0) & (x1 < W_);
        int cy0 = min(max(y0, 0), H_ - 1), cy1 = min(max(y1, 0), H_ - 1);
        int cx0 = min(max(x0, 0), W_ - 1), cx1 = min(max(x1, 0), W_ - 1);
        int4 ii; float4 ww;
        ii.x = cy0 * W_ + cx0;  ww.x = wy0 * wx0 * ((vy0 & vx0) ? 1.f : 0.f);
        ii.y = cy0 * W_ + cx1;  ww.y = wy0 * wx1 * ((vy0 & vx1) ? 1.f : 0.f);
        ii.z = cy1 * W_ + cx0;  ww.z = wy1 * wx0 * ((vy1 & vx0) ? 1.f : 0.f);
        ii.w = cy1 * W_ + cx1;  ww.w = wy1 * wx1 * ((vy1 & vx1) ? 1.f : 0.f);
        meta_i[e] = ii;
        meta_w[e] = ww;
    }

    const int px = tid >> 2;           // 0..63
    const int cg = tid & 3;            // 16-ch group for the gather
    const int wv = tid >> 6;
    const int ln = tid & 63;
    const int lo = ln & 15;
    const int quad = ln >> 4;

    f32x4 acc[4][4];
#pragma unroll
    for (int t = 0; t < 4; ++t)
#pragma unroll
        for (int p = 0; p < 4; ++p)
            acc[t][p] = (f32x4){0.f, 0.f, 0.f, 0.f};

    const unsigned short* xbb = xT + ((size_t)b << 20) + cg * 16;
    const int bwr = px * 8;            // bT row base for this thread's writes
    const int sw0 = (2 * cg)     ^ (px & 7);
    const int sw1 = (2 * cg + 1) ^ (px & 7);

    __syncthreads();                   // meta ready

    int4   cr[8];
    float4 wwp;
    // ---- prologue: gather stage 0 (k=0, c0=0) into bT[0] ----
    {
        int4 ii = meta_i[px];
        wwp = meta_w[px];
        const int4* pA = (const int4*)(xbb + ((size_t)ii.x << 8));
        const int4* pB = (const int4*)(xbb + ((size_t)ii.y << 8));
        const int4* pC = (const int4*)(xbb + ((size_t)ii.z << 8));
        const int4* pD = (const int4*)(xbb + ((size_t)ii.w << 8));
        cr[0] = pA[0]; cr[1] = pA[1];
        cr[2] = pB[0]; cr[3] = pB[1];
        cr[4] = pC[0]; cr[5] = pC[1];
        cr[6] = pD[0]; cr[7] = pD[1];
        int4 o0, o1;
        o0.x = pk2(wwp.x * up2(cr[0].x) + wwp.y * up2(cr[2].x) + wwp.z * up2(cr[4].x) + wwp.w * up2(cr[6].x));
        o0.y = pk2(wwp.x * up2(cr[0].y) + wwp.y * up2(cr[2].y) + wwp.z * up2(cr[4].y) + wwp.w * up2(cr[6].y));
        o0.z = pk2(wwp.x * up2(cr[0].z) + wwp.y * up2(cr[2].z) + wwp.z * up2(cr[4].z) + wwp.w * up2(cr[6].z));
        o0.w = pk2(wwp.x * up2(cr[0].w) + wwp.y * up2(cr[2].w) + wwp.z * up2(cr[4].w) + wwp.w * up2(cr[6].w));
        o1.x = pk2(wwp.x * up2(cr[1].x) + wwp.y * up2(cr[3].x) + wwp.z * up2(cr[5].x) + wwp.w * up2(cr[7].x));
        o1.y = pk2(wwp.x * up2(cr[1].y) + wwp.y * up2(cr[3].y) + wwp.z * up2(cr[5].y) + wwp.w * up2(cr[7].y));
        o1.z = pk2(wwp.x * up2(cr[1].z) + wwp.y * up2(cr[3].z) + wwp.z * up2(cr[5].z) + wwp.w * up2(cr[7].z));
        o1.w = pk2(wwp.x * up2(cr[1].w) + wwp.y * up2(cr[3].w) + wwp.z * up2(cr[5].w) + wwp.w * up2(cr[7].w));
        bT[0][bwr + sw0] = o0;
        bT[0][bwr + sw1] = o1;
    }

#pragma unroll 2
    for (int s = 0; s < 36; ++s) {
        __syncthreads();               // bT[s&1] ready; prior reads drained
        int c4 = s / 9, k = s - c4 * 9, c0 = c4 << 6;

        // ---- A fragments: direct from wR (L2-resident), non-temporal ----
        const short* wb = wR + k * 65536 + (wv * 64 + lo) * 256 + c0 + quad * 8;
        i32x4 aL[4][2];
#pragma unroll
        for (int t = 0; t < 4; ++t)
#pragma unroll
            for (int ks = 0; ks < 2; ++ks)
                aL[t][ks] = __builtin_nontemporal_load(
                    (const i32x4*)(wb + t * 4096 + ks * 32));

        // ---- issue corner loads for stage s+1 (overlap with MFMA) ----
        if (s < 35) {
            int s1 = s + 1;
            int c41 = s1 / 9, k1 = s1 - c41 * 9, c01 = c41 << 6;
            int4 ii = meta_i[k1 * 64 + px];
            wwp = meta_w[k1 * 64 + px];
            const unsigned short* xc = xbb + c01;
            const int4* pA = (const int4*)(xc + ((size_t)ii.x << 8));
            const int4* pB = (const int4*)(xc + ((size_t)ii.y << 8));
            const int4* pC = (const int4*)(xc + ((size_t)ii.z << 8));
            const int4* pD = (const int4*)(xc + ((size_t)ii.w << 8));
            cr[0] = pA[0]; cr[1] = pA[1];
            cr[2] = pB[0]; cr[3] = pB[1];
            cr[4] = pC[0]; cr[5] = pC[1];
            cr[6] = pD[0]; cr[7] = pD[1];
        }

        // ---- MFMA on bT[s&1] ----
#pragma unroll
        for (int ks = 0; ks < 2; ++ks) {
            short8 bfr[4];
#pragma unroll
            for (int p = 0; p < 4; ++p) {
                int pr = p * 16 + lo;
                bfr[p] = *(const short8*)&bT[s & 1][pr * 8 + ((ks * 4 + quad) ^ (pr & 7))];
            }
#pragma unroll
            for (int t = 0; t < 4; ++t) {
                cvt8 aa; aa.v = aL[t][ks];
#pragma unroll
                for (int p = 0; p < 4; ++p)
                    acc[t][p] = __builtin_amdgcn_mfma_f32_16x16x32_bf16(
                        aa.s, bfr[p], acc[t][p], 0, 0, 0);
            }
        }

        // ---- blend + write stage s+1 into bT[(s+1)&1] ----
        if (s < 35) {
            int4 o0, o1;
            o0.x = pk2(wwp.x * up2(cr[0].x) + wwp.y * up2(cr[2].x) + wwp.z * up2(cr[4].x) + wwp.w * up2(cr[6].x));
            o0.y = pk2(wwp.x * up2(cr[0].y) + wwp.y * up2(cr[2].y) + wwp.z * up2(cr[4].y) + wwp.w * up2(cr[6].y));
            o0.z = pk2(wwp.x * up2(cr[0].z) + wwp.y * up2(cr[2].z) + wwp.z * up2(cr[4].z) + wwp.w * up2(cr[6].z));
            o0.w = pk2(wwp.x * up2(cr[0].w) + wwp.y * up2(cr[2].w) + wwp.z * up2(cr[4].w) + wwp.w * up2(cr[6].w));
            o1.x = pk2(wwp.x * up2(cr[1].x) + wwp.y * up2(cr[3].x) + wwp.z * up2(cr[5].x) + wwp.w * up2(cr[7].x));
            o1.y = pk2(wwp.x * up2(cr[1].y) + wwp.y * up2(cr[3].y) + wwp.z * up2(cr[5].y) + wwp.w * up2(cr[7].y));
            o1.z = pk2(wwp.x * up2(cr[1].z) + wwp.y * up2(cr[3].z) + wwp.z * up2(cr[5].z) + wwp.w * up2(cr[7].z));
            o1.w = pk2(wwp.x * up2(cr[1].w) + wwp.y * up2(cr[3].w) + wwp.z * up2(cr[5].w) + wwp.w * up2(cr[7].w));
            bT[(s + 1) & 1][bwr + sw0] = o0;
            bT[(s + 1) & 1][bwr + sw1] = o1;
        }
    }

    // ---- epilogue: store y + per-(b,o) sum/sumsq atomics ----
    float* yb = y + ((size_t)b << 20) + ho * 64;
#pragma unroll
    for (int t = 0; t < 4; ++t) {
#pragma unroll
        for (int r = 0; r < 4; ++r) {
            int o = wv * 64 + t * 16 + quad * 4 + r;
            float sv = 0.f, qv = 0.f;
#pragma unroll
            for (int p = 0; p < 4; ++p) {
                float val = acc[t][p][r];
                yb[(size_t)o * HW + p * 16 + lo] = val;
                sv += val;
                qv += val * val;
            }
#pragma unroll
            for (int m = 1; m <= 8; m <<= 1) {
                sv += __shfl_xor(sv, m, 16);
                qv += __shfl_xor(qv, m, 16);
            }
            if (lo == 0) {
                atomicAdd(&sum_[b * COUT + o], sv);
                atomicAdd(&sumsq_[b * COUT + o], qv);
            }
        }
    }
}

// ---------------------------------------------------------------------------
// Channel attention (mean + unbiased std -> sigmoid) and scale.
// ---------------------------------------------------------------------------
__global__ __launch_bounds__(256) void attn_scale_kernel(
    const float* __restrict__ sum_, const float* __restrict__ sumsq_,
    float* __restrict__ y)
{
    int bo = blockIdx.x;
    float s = sum_[bo], q = sumsq_[bo];
    float mean = s * (1.f / 4096.f);
    float var  = (q - s * s * (1.f / 4096.f)) * (1.f / 4095.f);
    float sd   = sqrtf(fmaxf(var, 0.f));
    float attn = 1.f / (1.f + expf(-(mean + sd)));
    float4* yp = (float4*)(y + (size_t)bo * HW);
#pragma unroll
    for (int i = 0; i < 4; ++i) {
        float4 v = yp[threadIdx.x + i * 256];
        v.x *= attn; v.y *= attn; v.z *= attn; v.w *= attn;
        yp[threadIdx.x + i * 256] = v;
    }
}

// ---------------------------------------------------------------------------
extern "C" void kernel_launch(void* const* d_in, const int* in_sizes, int n_in,
                              void* d_out, int out_size, void* d_ws, size_t ws_size,
                              hipStream_t stream)
{
    const float* x  = (const float*)d_in[0];   // [8,256,64,64]
    const float* ow = (const float*)d_in[1];   // [18,256,3,3]
    const float* dw = (const float*)d_in[2];   // [256,256,3,3]
    float* out = (float*)d_out;                // [8,256,64,64]
    float* ws  = (float*)d_ws;

    float*          offs = ws;                              // 589824 f
    unsigned short* xT   = (unsigned short*)(ws + 589824);  // 8388608 us
    short*          wR   = (short*)(xT + 8388608);          // 589824
    short*          wO   = wR + 589824;                     // 73728
    float*          sum_ = (float*)(wO + 73728);            // 2048
    float*          sumsq_ = sum_ + 2048;                   // 2048

    hipMemsetAsync(sum_, 0, 2 * 2048 * sizeof(float), stream);

    prep_weights_kernel<<<9 * 288, 256, 0, stream>>>(ow, dw, wR, wO);
    transpose_x_kernel<<<512, 256, 0, stream>>>(x, xT);
    offset_mfma_kernel<<<512, 256, 0, stream>>>(xT, wO, offs);
    deform_mfma_kernel<<<512, 256, 0, stream>>>(xT, offs, wR, out, sum_, sumsq_);
    attn_scale_kernel<<<2048, 256, 0, stream>>>(sum_, sumsq_, out);
}

// Round 6
// 233.088 us; speedup vs baseline: 1.1893x; 1.1893x over previous
//
#include <hip/hip_runtime.h>
#include <hip/hip_bf16.h>
#include <math.h>

#define C_IN 256
#define H_   64
#define W_   64
#define B_   8
#define COUT 256
#define HW   (H_*W_)

typedef float f32x4 __attribute__((ext_vector_type(4)));
typedef float f32x2 __attribute__((ext_vector_type(2)));
typedef short short8 __attribute__((ext_vector_type(8)));
typedef int   i32x4 __attribute__((ext_vector_type(4)));

union cvt8 { i32x4 v; short8 s; };

static __device__ __forceinline__ int pack_bf16x2(float a, float b) {
    __hip_bfloat162 h = __float22bfloat162_rn(make_float2(a, b));
    union { __hip_bfloat162 h; int i; } u; u.h = h;
    return u.i;
}

static __device__ __forceinline__ f32x2 up2(int v) {
    union { int i; float f; } a, b;
    a.i = v << 16; b.i = v & 0xffff0000;
    return (f32x2){a.f, b.f};
}

// fp32 bilinear blend of 2 packed bf16 channels, repack to bf16x2
static __device__ __forceinline__ int blend2(int a, int b, int c, int d, float4 w) {
    f32x2 r = w.x * up2(a) + w.y * up2(b) + w.z * up2(c) + w.w * up2(d);
    return pack_bf16x2(r[0], r[1]);
}

// ---------------------------------------------------------------------------
// Prep: weights -> bf16 in MFMA *fragment order* so A-loads are one coalesced
// dwordx4 per lane.
//   wA [k][c4][ot16][ks2][lane64][8]   (deform, 589824 shorts)
//   wOA[k][c4][t2][ks2][lane64][8]     (offset, 73728 shorts, o>=18 zero)
// lane -> (m = lane&15, quad = lane>>4); o = ot*16+m; c = c4*64+ks*32+quad*8+j
// ---------------------------------------------------------------------------
__global__ __launch_bounds__(256) void prep_weights_kernel(
    const float* __restrict__ ow, const float* __restrict__ dw,
    short* __restrict__ wA, short* __restrict__ wOA)
{
    int blk = blockIdx.x;
    if (blk < 2304) {                       // wA: 2304*256 elems
        int e  = blk * 256 + threadIdx.x;
        int j  = e & 7;
        int ln = (e >> 3) & 63;
        int ks = (e >> 9) & 1;
        int ot = (e >> 10) & 15;
        int c4 = (e >> 14) & 3;
        int k  = e >> 16;
        int o  = ot * 16 + (ln & 15);
        int c  = c4 * 64 + ks * 32 + (ln >> 4) * 8 + j;
        union { float f; unsigned u; } a;
        a.f = dw[((size_t)o * 256 + c) * 9 + k];
        unsigned r = (a.u + 0x7fffu + ((a.u >> 16) & 1u)) >> 16;
        wA[e] = (short)r;
    } else {                                // wOA: 288*256 elems
        int e  = (blk - 2304) * 256 + threadIdx.x;
        int j  = e & 7;
        int ln = (e >> 3) & 63;
        int ks = (e >> 9) & 1;
        int t  = (e >> 10) & 1;
        int c4 = (e >> 11) & 3;
        int k  = e >> 13;
        int o  = t * 16 + (ln & 15);
        int c  = c4 * 64 + ks * 32 + (ln >> 4) * 8 + j;
        union { float f; unsigned u; } a;
        a.f = (o < 18) ? ow[((size_t)o * 256 + c) * 9 + k] : 0.f;
        unsigned r = (a.u + 0x7fffu + ((a.u >> 16) & 1u)) >> 16;
        wOA[e] = (short)r;
    }
}

// ---------------------------------------------------------------------------
// Transpose x: NCHW fp32 -> NHWC bf16  xT[b][h][w][c]. One block per (b,h).
// ---------------------------------------------------------------------------
__global__ __launch_bounds__(256) void transpose_x_kernel(
    const float* __restrict__ x, unsigned short* __restrict__ xT)
{
    __shared__ float tile[64][257];
    const int tid = threadIdx.x;
    const float* xb = x + ((size_t)(blockIdx.x >> 6) << 20) + (blockIdx.x & 63) * 64;

#pragma unroll
    for (int pass = 0; pass < 16; ++pass) {
        int c  = pass * 16 + (tid >> 4);
        int w0 = (tid & 15) * 4;
        float4 v = *(const float4*)(xb + (size_t)c * 4096 + w0);
        tile[w0][c] = v.x; tile[w0 + 1][c] = v.y;
        tile[w0 + 2][c] = v.z; tile[w0 + 3][c] = v.w;
    }
    __syncthreads();

    int4* ob = (int4*)(xT + ((size_t)blockIdx.x << 14));
#pragma unroll
    for (int pass = 0; pass < 8; ++pass) {
        int idx = pass * 256 + tid;
        int w = idx >> 5, ch8 = idx & 31;
        const float* tr = &tile[w][ch8 * 8];
        int4 pk;
        pk.x = pack_bf16x2(tr[0], tr[1]);
        pk.y = pack_bf16x2(tr[2], tr[3]);
        pk.z = pack_bf16x2(tr[4], tr[5]);
        pk.w = pack_bf16x2(tr[6], tr[7]);
        ob[idx] = pk;
    }
}

// ---------------------------------------------------------------------------
// Offset conv via bf16 MFMA. Zero LDS, zero barriers, tap-major stage order,
// one-stage prefetch of A and B. One block per (b,ho), b = blk&7 (XCD pin).
// ---------------------------------------------------------------------------
__global__ __launch_bounds__(256, 4) void offset_mfma_kernel(
    const unsigned short* __restrict__ xT, const short* __restrict__ wOA,
    float* __restrict__ offs)
{
    const int tid = threadIdx.x;
    const int b   = blockIdx.x & 7;
    const int ho  = blockIdx.x >> 3;

    const int wv = tid >> 6;
    const int ln = tid & 63;
    const int lo = ln & 15;
    const int quad = ln >> 4;
    const int pxl = wv * 16 + lo;

    f32x4 acc[2];
    acc[0] = (f32x4){0.f, 0.f, 0.f, 0.f};
    acc[1] = (f32x4){0.f, 0.f, 0.f, 0.f};

    const unsigned short* xbb = xT + ((size_t)b << 20);
    const i32x4 z4 = {0, 0, 0, 0};

    i32x4 bB[2][2], aB[2][2][2];

    // prologue: stage 0 (k=0, c0=0)
    {
        int yy = ho - 1, xx = pxl - 1;
        bool valid = (yy >= 0) & (xx >= 0);
        int yc = max(yy, 0), xc = max(xx, 0);
        const unsigned short* src = xbb + (((size_t)yc * 64 + xc) << 8) + quad * 8;
#pragma unroll
        for (int ks = 0; ks < 2; ++ks)
            bB[0][ks] = valid ? *(const i32x4*)(src + ks * 32) : z4;
        const i32x4* wb = (const i32x4*)wOA + ln;   // k=0,c4=0
#pragma unroll
        for (int t = 0; t < 2; ++t)
#pragma unroll
            for (int ks = 0; ks < 2; ++ks)
                aB[0][t][ks] = wb[(t * 2 + ks) * 64];
    }

#pragma unroll 4
    for (int s = 0; s < 36; ++s) {
        int cur = s & 1;
        if (s < 35) {
            int s1 = s + 1, k1 = s1 >> 2, c41 = s1 & 3;
            int yy = ho + k1 / 3 - 1;
            int xx = pxl + k1 % 3 - 1;
            bool valid = (yy >= 0) & (yy < 64) & (xx >= 0) & (xx < 64);
            int yc = min(max(yy, 0), 63), xc = min(max(xx, 0), 63);
            const unsigned short* src =
                xbb + (((size_t)yc * 64 + xc) << 8) + c41 * 64 + quad * 8;
#pragma unroll
            for (int ks = 0; ks < 2; ++ks)
                bB[cur ^ 1][ks] = valid ? *(const i32x4*)(src + ks * 32) : z4;
            const i32x4* wb = (const i32x4*)wOA + ((k1 * 4 + c41) * 4) * 64 + ln;
#pragma unroll
            for (int t = 0; t < 2; ++t)
#pragma unroll
                for (int ks = 0; ks < 2; ++ks)
                    aB[cur ^ 1][t][ks] = wb[(t * 2 + ks) * 64];
        }
#pragma unroll
        for (int ks = 0; ks < 2; ++ks) {
            cvt8 bb; bb.v = bB[cur][ks];
#pragma unroll
            for (int t = 0; t < 2; ++t) {
                cvt8 aa; aa.v = aB[cur][t][ks];
                acc[t] = __builtin_amdgcn_mfma_f32_16x16x32_bf16(aa.s, bb.s, acc[t], 0, 0, 0);
            }
        }
    }

#pragma unroll
    for (int t = 0; t < 2; ++t) {
#pragma unroll
        for (int r = 0; r < 4; ++r) {
            int o = t * 16 + quad * 4 + r;
            if (o < 18)
                offs[((size_t)b * 18 + o) * HW + ho * 64 + pxl] = acc[t][r];
        }
    }
}

// ---------------------------------------------------------------------------
// Deformable conv via bf16 MFMA. One block per (b,ho), b = blk&7 (XCD pin).
// 64 px x 256 o. Tap-major stages (corner L1 streaming). A fragments direct
// global->VGPR from fragment-ordered wA (coalesced), one-stage prefetch.
// B: bilinear blend -> double-buffered LDS; ONE barrier per stage.
// ---------------------------------------------------------------------------
__global__ __launch_bounds__(256, 2) void deform_mfma_kernel(
    const unsigned short* __restrict__ xT, const float* __restrict__ offs,
    const short* __restrict__ wA, float* __restrict__ y,
    float* __restrict__ sum_, float* __restrict__ sumsq_)
{
    __shared__ i32x4  meta_i[576];
    __shared__ float4 meta_w[576];
    __shared__ i32x4  bT[2][64 * 8];

    const int tid = threadIdx.x;
    const int b   = blockIdx.x & 7;
    const int ho  = blockIdx.x >> 3;

    for (int e = tid; e < 576; e += 256) {
        int kk = e >> 6;
        int pxe = e & 63;
        float dy = offs[((size_t)b * 18 + 2 * kk)     * HW + ho * W_ + pxe];
        float dx = offs[((size_t)b * 18 + 2 * kk + 1) * HW + ho * W_ + pxe];
        float sy = (float)(ho - 1 + kk / 3) + dy;
        float sx = (float)(pxe - 1 + kk % 3) + dx;
        float y0f = floorf(sy), x0f = floorf(sx);
        float ly = sy - y0f, lx = sx - x0f;
        int y0 = (int)y0f, x0 = (int)x0f;
        int y1 = y0 + 1, x1 = x0 + 1;
        float wy0 = 1.f - ly, wy1 = ly, wx0 = 1.f - lx, wx1 = lx;
        bool vy0 = (y0 >= 0) & (y0 < H_), vy1 = (y1 >= 0) & (y1 < H_);
        bool vx0 = (x0 >= 0) & (x0 < W_), vx1 = (x1 >= 0) & (x1 < W_);
        int cy0 = min(max(y0, 0), H_ - 1), cy1 = min(max(y1, 0), H_ - 1);
        int cx0 = min(max(x0, 0), W_ - 1), cx1 = min(max(x1, 0), W_ - 1);
        i32x4 ii; float4 ww;
        ii.x = cy0 * W_ + cx0;  ww.x = wy0 * wx0 * ((vy0 & vx0) ? 1.f : 0.f);
        ii.y = cy0 * W_ + cx1;  ww.y = wy0 * wx1 * ((vy0 & vx1) ? 1.f : 0.f);
        ii.z = cy1 * W_ + cx0;  ww.z = wy1 * wx0 * ((vy1 & vx0) ? 1.f : 0.f);
        ii.w = cy1 * W_ + cx1;  ww.w = wy1 * wx1 * ((vy1 & vx1) ? 1.f : 0.f);
        meta_i[e] = ii;
        meta_w[e] = ww;
    }

    const int px = tid >> 2;           // 0..63
    const int cg = tid & 3;            // 16-ch group for the gather
    const int wv = tid >> 6;
    const int ln = tid & 63;
    const int lo = ln & 15;
    const int quad = ln >> 4;

    f32x4 acc[4][4];
#pragma unroll
    for (int t = 0; t < 4; ++t)
#pragma unroll
        for (int p = 0; p < 4; ++p)
            acc[t][p] = (f32x4){0.f, 0.f, 0.f, 0.f};

    const unsigned short* xbb = xT + ((size_t)b << 20) + cg * 16;
    const int bwr = px * 8;
    const int sw0 = (2 * cg)     ^ (px & 7);
    const int sw1 = (2 * cg + 1) ^ (px & 7);

    __syncthreads();                   // meta ready

    i32x4 cr[8];
    float4 wwp;
    i32x4 aB[2][4][2];

    // ---- prologue: stage 0 (k=0, c4=0): corners+blend -> bT[0]; A -> aB[0]
    {
        i32x4 ii = meta_i[px];
        wwp = meta_w[px];
        const i32x4* pA = (const i32x4*)(xbb + ((size_t)ii.x << 8));
        const i32x4* pB = (const i32x4*)(xbb + ((size_t)ii.y << 8));
        const i32x4* pC = (const i32x4*)(xbb + ((size_t)ii.z << 8));
        const i32x4* pD = (const i32x4*)(xbb + ((size_t)ii.w << 8));
        cr[0] = pA[0]; cr[1] = pA[1];
        cr[2] = pB[0]; cr[3] = pB[1];
        cr[4] = pC[0]; cr[5] = pC[1];
        cr[6] = pD[0]; cr[7] = pD[1];
        const i32x4* wb = (const i32x4*)wA + (wv * 4) * 2 * 64 + ln;
#pragma unroll
        for (int t = 0; t < 4; ++t)
#pragma unroll
            for (int ks = 0; ks < 2; ++ks)
                aB[0][t][ks] = wb[(t * 2 + ks) * 64];
        i32x4 o0, o1;
        o0.x = blend2(cr[0].x, cr[2].x, cr[4].x, cr[6].x, wwp);
        o0.y = blend2(cr[0].y, cr[2].y, cr[4].y, cr[6].y, wwp);
        o0.z = blend2(cr[0].z, cr[2].z, cr[4].z, cr[6].z, wwp);
        o0.w = blend2(cr[0].w, cr[2].w, cr[4].w, cr[6].w, wwp);
        o1.x = blend2(cr[1].x, cr[3].x, cr[5].x, cr[7].x, wwp);
        o1.y = blend2(cr[1].y, cr[3].y, cr[5].y, cr[7].y, wwp);
        o1.z = blend2(cr[1].z, cr[3].z, cr[5].z, cr[7].z, wwp);
        o1.w = blend2(cr[1].w, cr[3].w, cr[5].w, cr[7].w, wwp);
        bT[0][bwr + sw0] = o0;
        bT[0][bwr + sw1] = o1;
    }

#pragma unroll 2
    for (int s = 0; s < 36; ++s) {
        __syncthreads();               // bT[s&1] + prefetched A drained
        const int cur = s & 1;

        // ---- prefetch stage s+1: corners (regs) + A fragments ----
        if (s < 35) {
            int s1 = s + 1, k1 = s1 >> 2, c41 = s1 & 3;
            i32x4 ii = meta_i[k1 * 64 + px];
            wwp = meta_w[k1 * 64 + px];
            const unsigned short* xc = xbb + c41 * 64;
            const i32x4* pA = (const i32x4*)(xc + ((size_t)ii.x << 8));
            const i32x4* pB = (const i32x4*)(xc + ((size_t)ii.y << 8));
            const i32x4* pC = (const i32x4*)(xc + ((size_t)ii.z << 8));
            const i32x4* pD = (const i32x4*)(xc + ((size_t)ii.w << 8));
            cr[0] = pA[0]; cr[1] = pA[1];
            cr[2] = pB[0]; cr[3] = pB[1];
            cr[4] = pC[0]; cr[5] = pC[1];
            cr[6] = pD[0]; cr[7] = pD[1];
            const i32x4* wb = (const i32x4*)wA
                + (((k1 * 4 + c41) * 16 + wv * 4) * 2) * 64 + ln;
#pragma unroll
            for (int t = 0; t < 4; ++t)
#pragma unroll
                for (int ks = 0; ks < 2; ++ks)
                    aB[cur ^ 1][t][ks] = wb[(t * 2 + ks) * 64];
        }

        // ---- MFMA on bT[cur] with aB[cur] ----
#pragma unroll
        for (int ks = 0; ks < 2; ++ks) {
            short8 bfr[4];
#pragma unroll
            for (int p = 0; p < 4; ++p) {
                int pr = p * 16 + lo;
                bfr[p] = *(const short8*)&bT[cur][pr * 8 + ((ks * 4 + quad) ^ (pr & 7))];
            }
#pragma unroll
            for (int t = 0; t < 4; ++t) {
                cvt8 aa; aa.v = aB[cur][t][ks];
#pragma unroll
                for (int p = 0; p < 4; ++p)
                    acc[t][p] = __builtin_amdgcn_mfma_f32_16x16x32_bf16(
                        aa.s, bfr[p], acc[t][p], 0, 0, 0);
            }
        }

        // ---- blend + write stage s+1 into bT[cur^1] ----
        if (s < 35) {
            i32x4 o0, o1;
            o0.x = blend2(cr[0].x, cr[2].x, cr[4].x, cr[6].x, wwp);
            o0.y = blend2(cr[0].y, cr[2].y, cr[4].y, cr[6].y, wwp);
            o0.z = blend2(cr[0].z, cr[2].z, cr[4].z, cr[6].z, wwp);
            o0.w = blend2(cr[0].w, cr[2].w, cr[4].w, cr[6].w, wwp);
            o1.x = blend2(cr[1].x, cr[3].x, cr[5].x, cr[7].x, wwp);
            o1.y = blend2(cr[1].y, cr[3].y, cr[5].y, cr[7].y, wwp);
            o1.z = blend2(cr[1].z, cr[3].z, cr[5].z, cr[7].z, wwp);
            o1.w = blend2(cr[1].w, cr[3].w, cr[5].w, cr[7].w, wwp);
            bT[cur ^ 1][bwr + sw0] = o0;
            bT[cur ^ 1][bwr + sw1] = o1;
        }
    }

    // ---- epilogue: store y + per-(b,o) sum/sumsq atomics ----
    float* yb = y + ((size_t)b << 20) + ho * 64;
#pragma unroll
    for (int t = 0; t < 4; ++t) {
#pragma unroll
        for (int r = 0; r < 4; ++r) {
            int o = wv * 64 + t * 16 + quad * 4 + r;
            float sv = 0.f, qv = 0.f;
#pragma unroll
            for (int p = 0; p < 4; ++p) {
                float val = acc[t][p][r];
                yb[(size_t)o * HW + p * 16 + lo] = val;
                sv += val;
                qv += val * val;
            }
#pragma unroll
            for (int m = 1; m <= 8; m <<= 1) {
                sv += __shfl_xor(sv, m, 16);
                qv += __shfl_xor(qv, m, 16);
            }
            if (lo == 0) {
                atomicAdd(&sum_[b * COUT + o], sv);
                atomicAdd(&sumsq_[b * COUT + o], qv);
            }
        }
    }
}

// ---------------------------------------------------------------------------
// Channel attention (mean + unbiased std -> sigmoid) and scale.
// ---------------------------------------------------------------------------
__global__ __launch_bounds__(256) void attn_scale_kernel(
    const float* __restrict__ sum_, const float* __restrict__ sumsq_,
    float* __restrict__ y)
{
    int bo = blockIdx.x;
    float s = sum_[bo], q = sumsq_[bo];
    float mean = s * (1.f / 4096.f);
    float var  = (q - s * s * (1.f / 4096.f)) * (1.f / 4095.f);
    float sd   = sqrtf(fmaxf(var, 0.f));
    float attn = 1.f / (1.f + expf(-(mean + sd)));
    float4* yp = (float4*)(y + (size_t)bo * HW);
#pragma unroll
    for (int i = 0; i < 4; ++i) {
        float4 v = yp[threadIdx.x + i * 256];
        v.x *= attn; v.y *= attn; v.z *= attn; v.w *= attn;
        yp[threadIdx.x + i * 256] = v;
    }
}

// ---------------------------------------------------------------------------
extern "C" void kernel_launch(void* const* d_in, const int* in_sizes, int n_in,
                              void* d_out, int out_size, void* d_ws, size_t ws_size,
                              hipStream_t stream)
{
    const float* x  = (const float*)d_in[0];   // [8,256,64,64]
    const float* ow = (const float*)d_in[1];   // [18,256,3,3]
    const float* dw = (const float*)d_in[2];   // [256,256,3,3]
    float* out = (float*)d_out;                // [8,256,64,64]
    float* ws  = (float*)d_ws;

    float*          offs = ws;                              // 589824 f
    unsigned short* xT   = (unsigned short*)(ws + 589824);  // 8388608 us
    short*          wA   = (short*)(xT + 8388608);          // 589824
    short*          wOA  = wA + 589824;                     // 73728
    float*          sum_ = (float*)(wOA + 73728);           // 2048
    float*          sumsq_ = sum_ + 2048;                   // 2048

    hipMemsetAsync(sum_, 0, 2 * 2048 * sizeof(float), stream);

    prep_weights_kernel<<<2304 + 288, 256, 0, stream>>>(ow, dw, wA, wOA);
    transpose_x_kernel<<<512, 256, 0, stream>>>(x, xT);
    offset_mfma_kernel<<<512, 256, 0, stream>>>(xT, wOA, offs);
    deform_mfma_kernel<<<512, 256, 0, stream>>>(xT, offs, wA, out, sum_, sumsq_);
    attn_scale_kernel<<<2048, 256, 0, stream>>>(sum_, sumsq_, out);
}